// Round 1
// baseline (2424.493 us; speedup 1.0000x reference)
//
#include <hip/hip_runtime.h>
#include <hip/hip_bf16.h>

// ---------------------------------------------------------------------------
// Net_15762529976343: STN-style head on MI355X.
// All five big ops are GEMMs with K=18432, N=200 sharing one kernel:
//   conv_last / loc1 / loc2 : M=2048, B = im2col(input)
//   fc1                     : M=512,  B = im2col(xs)      (patches == im2col!)
//   conv_stn                : M=201,  B = grid_sample out in im2col layout
// Round 1: fp32 everywhere, correctness-first.
// ---------------------------------------------------------------------------

#define GN 200        // N = B*5*5
#define GK 18432      // K = 2048*9
#define KSPLIT 4
#define KCHUNK (GK / KSPLIT)   // 4608

// ---------------- im2col: in [8,2048,H,H] -> Bmat [18432,200] --------------
__global__ __launch_bounds__(256) void im2col_kernel(
    const float* __restrict__ in, float* __restrict__ Bmat,
    int H, int stride, int pad)
{
    int tid = blockIdx.x * 256 + threadIdx.x;
    if (tid >= GK * GN) return;
    int n = tid % GN;
    int k = tid / GN;
    int c = k / 9;
    int r9 = k % 9;
    int kh = r9 / 3, kw = r9 % 3;
    int b = n / 25;
    int pp = n % 25;
    int oh = pp / 5, ow = pp % 5;
    int r = oh * stride + kh - pad;
    int s = ow * stride + kw - pad;
    float v = 0.0f;
    if (r >= 0 && r < H && s >= 0 && s < H)
        v = in[(((b * 2048 + c) * H) + r) * H + s];
    Bmat[tid] = v;
}

// ---------------- GEMM: C[M,200] += A[M,18432] * B[18432,200] --------------
// 64x64 tile, 4x4 micro-tile, BK=16, K-split over blockIdx.z with atomicAdd.
__global__ __launch_bounds__(256) void gemm200(
    const float* __restrict__ A, const float* __restrict__ B,
    float* __restrict__ C, int M)
{
    __shared__ float As[16][64];   // [k][m]
    __shared__ float Bs[16][64];   // [k][n]

    const int bm = blockIdx.x * 64;
    const int bn = blockIdx.y * 64;
    const int kbase = blockIdx.z * KCHUNK;
    const int tid = threadIdx.x;

    const int tm = (tid >> 4) << 2;   // 0..60
    const int tn = (tid & 15) << 2;   // 0..60

    // A staging: thread loads 4 consecutive k of one row
    const int ar = tid >> 2;          // 0..63 (row within tile)
    const int ak = (tid & 3) << 2;    // 0,4,8,12
    // B staging: thread loads 4 consecutive n of one k-row
    const int bk = tid >> 4;          // 0..15
    const int bnc = (tid & 15) << 2;  // 0..60

    const bool arow_ok = (bm + ar) < M;
    const float* Aptr = A + (size_t)(bm + ar) * GK + ak;
    const int ncol = bn + bnc;

    float acc[4][4] = {};

    for (int k0 = kbase; k0 < kbase + KCHUNK; k0 += 16) {
        float4 av = make_float4(0.f, 0.f, 0.f, 0.f);
        if (arow_ok) av = *(const float4*)(Aptr + k0);
        As[ak + 0][ar] = av.x;
        As[ak + 1][ar] = av.y;
        As[ak + 2][ar] = av.z;
        As[ak + 3][ar] = av.w;

        float4 bv = make_float4(0.f, 0.f, 0.f, 0.f);
        if (ncol + 3 < GN)   // GN=200: tiles at bn=192 are all-in or all-out per float4
            bv = *(const float4*)(B + (size_t)(k0 + bk) * GN + ncol);
        *(float4*)&Bs[bk][bnc] = bv;

        __syncthreads();
#pragma unroll
        for (int kk = 0; kk < 16; ++kk) {
            float4 a = *(const float4*)&As[kk][tm];
            float4 b = *(const float4*)&Bs[kk][tn];
            float aa[4] = {a.x, a.y, a.z, a.w};
            float bb[4] = {b.x, b.y, b.z, b.w};
#pragma unroll
            for (int i = 0; i < 4; ++i)
#pragma unroll
                for (int j = 0; j < 4; ++j)
                    acc[i][j] += aa[i] * bb[j];
        }
        __syncthreads();
    }

#pragma unroll
    for (int i = 0; i < 4; ++i) {
        int m = bm + tm + i;
        if (m >= M) continue;
#pragma unroll
        for (int j = 0; j < 4; ++j) {
            int n = bn + tn + j;
            if (n < GN) atomicAdd(&C[(size_t)m * GN + n], acc[i][j]);
        }
    }
}

// -------- BN stats: per-channel mean/rstd over 200 values (GEMM layout) ----
__global__ void bnstats_kernel(const float* __restrict__ y,
                               float* __restrict__ meanb,
                               float* __restrict__ rstdb)
{
    int ch = blockIdx.x;
    int lane = threadIdx.x;   // 64 threads
    const float* p = y + (size_t)ch * GN;
    float s = 0.f, sq = 0.f;
    for (int idx = lane; idx < GN; idx += 64) {
        float v = p[idx];
        s += v; sq += v * v;
    }
    for (int off = 32; off; off >>= 1) {
        s += __shfl_down(s, off);
        sq += __shfl_down(sq, off);
    }
    if (lane == 0) {
        float m = s * (1.f / 200.f);
        float var = sq * (1.f / 200.f) - m * m;   // ddof=0, matches jnp.var
        meanb[ch] = m;
        rstdb[ch] = rsqrtf(var + 1e-5f);
    }
}

// -------- BN apply + optional relu; GEMM layout [co][n] -> NCHW [b,c,5,5] --
__global__ __launch_bounds__(256) void bn_apply_kernel(
    const float* __restrict__ y, const float* __restrict__ meanb,
    const float* __restrict__ rstdb, const float* __restrict__ g,
    const float* __restrict__ bb, float* __restrict__ out, int relu)
{
    int tid = blockIdx.x * 256 + threadIdx.x;   // 8*2048*25 = 409600
    if (tid >= 409600) return;
    int b = tid / (2048 * 25);
    int rem = tid % (2048 * 25);
    int c = rem / 25;
    int pp = rem % 25;
    float v = y[(size_t)c * GN + b * 25 + pp];
    v = (v - meanb[c]) * rstdb[c] * g[c] + bb[c];
    if (relu) v = fmaxf(v, 0.f);
    out[tid] = v;
}

// -------- fc2: p[n,4] = relu(hmat)[.,n] . fc2_w  (relu folded here) --------
__global__ void fc2_kernel(const float* __restrict__ hmat,
                           const float* __restrict__ fc2w,
                           float* __restrict__ pbuf)
{
    int n = blockIdx.x;            // 0..199
    int oo = threadIdx.x >> 6;     // 0..3
    int lane = threadIdx.x & 63;
    float s = 0.f;
#pragma unroll
    for (int j = 0; j < 8; ++j) {
        int hh = lane + 64 * j;
        s += fmaxf(hmat[(size_t)hh * GN + n], 0.f) * fc2w[oo * 512 + hh];
    }
    for (int off = 32; off; off >>= 1) s += __shfl_down(s, off);
    if (lane == 0) pbuf[n * 4 + oo] = s;
}

// -------- theta (to d_out) + sampling grid pixel coords --------------------
__global__ void theta_grids_kernel(const float* __restrict__ pbuf,
                                   float* __restrict__ gridb,
                                   float* __restrict__ outT)
{
    int tid = blockIdx.x * 256 + threadIdx.x;   // 8*225 = 1800
    if (tid >= 1800) return;
    int b = tid / 225;
    int rem = tid % 225;
    int p = rem / 9;
    int k = rem % 9;
    int i = p / 5, j = p % 5;
    int dy = k / 3, dx = k % 3;
    int n = b * 25 + p;
    float p0 = pbuf[n * 4 + 0];
    float p1 = pbuf[n * 4 + 1];
    float p2 = pbuf[n * 4 + 2];
    float p3 = pbuf[n * 4 + 3];
    float x = (float)(j + dx) * (1.f / 3.f) - 1.f;   // lin[j+dx]
    float y = (float)(i + dy) * (1.f / 3.f) - 1.f;   // lin[i+dy]
    float gx = (1.f + p0) * x + p1;
    float gy = (1.f + p2) * y + p3;
    gridb[tid * 2 + 0] = (gx + 1.f) * 3.f;   // *(W-1)/2, W=7
    gridb[tid * 2 + 1] = (gy + 1.f) * 3.f;
    if (k == 0) {   // theta [200,2,3]
        outT[n * 6 + 0] = 1.f + p0;
        outT[n * 6 + 1] = 0.f;
        outT[n * 6 + 2] = p1;
        outT[n * 6 + 3] = 0.f;
        outT[n * 6 + 4] = 1.f + p2;
        outT[n * 6 + 5] = p3;
    }
}

// -------- grid_sample of padded f (7x7, zero ring) -> im2col layout --------
__global__ __launch_bounds__(256) void gridsample_kernel(
    const float* __restrict__ f, const float* __restrict__ gridb,
    float* __restrict__ Bstn)
{
    int tid = blockIdx.x * 256 + threadIdx.x;
    if (tid >= GK * GN) return;
    int n = tid % GN;
    int cq = tid / GN;
    int c = cq / 9;
    int q = cq % 9;
    int b = n / 25;
    int p = n % 25;
    int g = (b * 225 + p * 9 + q) * 2;
    float px = gridb[g], py = gridb[g + 1];
    float x0f = floorf(px), y0f = floorf(py);
    int x0 = (int)x0f, y0 = (int)y0f;
    float wx1 = px - x0f, wx0 = 1.f - wx1;
    float wy1 = py - y0f, wy0 = 1.f - wy1;
    const float* fb = f + ((size_t)b * 2048 + c) * 25;
    // f_p[y][x] nonzero only for 1<=x<=5, 1<=y<=5 (zero pad ring + OOB zero)
    auto fetch = [&](int xi, int yi) -> float {
        if (xi < 1 || xi > 5 || yi < 1 || yi > 5) return 0.f;
        return fb[(yi - 1) * 5 + (xi - 1)];
    };
    float v = fetch(x0, y0) * wx0 * wy0
            + fetch(x0 + 1, y0) * wx1 * wy0
            + fetch(x0, y0 + 1) * wx0 * wy1
            + fetch(x0 + 1, y0 + 1) * wx1 * wy1;
    Bstn[tid] = v;
}

// -------- softmax over 201*25 per batch (+bias), s + classif ---------------
__global__ void softmax_kernel(const float* __restrict__ stn,
                               const float* __restrict__ bias,
                               float* __restrict__ outC,
                               float* __restrict__ outS)
{
    int b = blockIdx.x;
    __shared__ float red[256];
    int t = threadIdx.x;

    float mx = -1e30f;
    for (int idx = t; idx < 5025; idx += 256) {
        int o = idx / 25, pp = idx % 25;
        mx = fmaxf(mx, stn[(size_t)o * GN + b * 25 + pp] + bias[o]);
    }
    red[t] = mx; __syncthreads();
    for (int s = 128; s; s >>= 1) {
        if (t < s) red[t] = fmaxf(red[t], red[t + s]);
        __syncthreads();
    }
    mx = red[0]; __syncthreads();

    float sm = 0.f;
    for (int idx = t; idx < 5025; idx += 256) {
        int o = idx / 25, pp = idx % 25;
        sm += expf(stn[(size_t)o * GN + b * 25 + pp] + bias[o] - mx);
    }
    red[t] = sm; __syncthreads();
    for (int s = 128; s; s >>= 1) {
        if (t < s) red[t] += red[t + s];
        __syncthreads();
    }
    float inv = 1.f / red[0];

    for (int idx = t; idx < 5025; idx += 256) {
        int o = idx / 25, pp = idx % 25;
        outS[b * 5025 + idx] =
            expf(stn[(size_t)o * GN + b * 25 + pp] + bias[o] - mx) * inv;
    }
    for (int o = t; o < 201; o += 256) {
        float cs = 0.f;
        for (int pp = 0; pp < 25; ++pp)
            cs += expf(stn[(size_t)o * GN + b * 25 + pp] + bias[o] - mx);
        outC[b * 201 + o] = cs * inv;
    }
}

// ---------------------------------------------------------------------------
extern "C" void kernel_launch(void* const* d_in, const int* in_sizes, int n_in,
                              void* d_out, int out_size, void* d_ws, size_t ws_size,
                              hipStream_t stream)
{
    const float* x           = (const float*)d_in[0];
    const float* conv_last_w = (const float*)d_in[3];
    const float* bn_last_g   = (const float*)d_in[4];
    const float* bn_last_b   = (const float*)d_in[5];
    const float* loc_w1      = (const float*)d_in[6];
    const float* loc_g1      = (const float*)d_in[7];
    const float* loc_b1      = (const float*)d_in[8];
    const float* loc_w2      = (const float*)d_in[9];
    const float* loc_g2      = (const float*)d_in[10];
    const float* loc_b2      = (const float*)d_in[11];
    const float* fc1_w       = (const float*)d_in[12];
    const float* fc2_w       = (const float*)d_in[13];
    const float* conv_stn_w  = (const float*)d_in[14];
    const float* conv_stn_b  = (const float*)d_in[15];

    float* ws    = (float*)d_ws;
    float* Bmat  = ws;                       // 3,686,400 (reused for samp)
    float* t1    = Bmat + 3686400;           // 409,600 (conv out, GEMM layout)
    float* fbuf  = t1 + 409600;              // 409,600 f NCHW
    float* xs1   = fbuf + 409600;            // 409,600
    float* xs    = xs1 + 409600;             // 409,600
    float* hmat  = xs + 409600;              // 102,400 (512 x 200)
    float* stn   = hmat + 102400;            // 40,200 (201 x 200)
    float* pbuf  = stn + 40200;              // 800
    float* gridb = pbuf + 800;               // 3,600
    float* meanb = gridb + 3600;             // 2,048
    float* rstdb = meanb + 2048;             // 2,048
    // total ~21.9 MB

    float* outC = (float*)d_out;             // [8,201]
    float* outS = outC + 8 * 201;            // [8,201,5,5]
    float* outT = outS + 8 * 201 * 25;       // [200,2,3]

    dim3 b256(256);
    int nIm = (GK * GN + 255) / 256;         // 14400 blocks

    // --- backbone tail: conv_last(s2,p1) + bn_last -> fbuf [8,2048,5,5]
    im2col_kernel<<<nIm, b256, 0, stream>>>(x, Bmat, 10, 2, 1);
    hipMemsetAsync(t1, 0, 409600 * sizeof(float), stream);
    gemm200<<<dim3(32, 4, KSPLIT), b256, 0, stream>>>(conv_last_w, Bmat, t1, 2048);
    bnstats_kernel<<<2048, 64, 0, stream>>>(t1, meanb, rstdb);
    bn_apply_kernel<<<1600, b256, 0, stream>>>(t1, meanb, rstdb, bn_last_g, bn_last_b, fbuf, 0);

    // --- loc conv1 + bn + relu -> xs1
    im2col_kernel<<<nIm, b256, 0, stream>>>(fbuf, Bmat, 5, 1, 1);
    hipMemsetAsync(t1, 0, 409600 * sizeof(float), stream);
    gemm200<<<dim3(32, 4, KSPLIT), b256, 0, stream>>>(loc_w1, Bmat, t1, 2048);
    bnstats_kernel<<<2048, 64, 0, stream>>>(t1, meanb, rstdb);
    bn_apply_kernel<<<1600, b256, 0, stream>>>(t1, meanb, rstdb, loc_g1, loc_b1, xs1, 1);

    // --- loc conv2 + bn + relu -> xs
    im2col_kernel<<<nIm, b256, 0, stream>>>(xs1, Bmat, 5, 1, 1);
    hipMemsetAsync(t1, 0, 409600 * sizeof(float), stream);
    gemm200<<<dim3(32, 4, KSPLIT), b256, 0, stream>>>(loc_w2, Bmat, t1, 2048);
    bnstats_kernel<<<2048, 64, 0, stream>>>(t1, meanb, rstdb);
    bn_apply_kernel<<<1600, b256, 0, stream>>>(t1, meanb, rstdb, loc_g2, loc_b2, xs, 1);

    // --- fc1: patches == im2col(xs, s1, p1); relu folded into fc2 read
    im2col_kernel<<<nIm, b256, 0, stream>>>(xs, Bmat, 5, 1, 1);
    hipMemsetAsync(hmat, 0, 102400 * sizeof(float), stream);
    gemm200<<<dim3(8, 4, KSPLIT), b256, 0, stream>>>(fc1_w, Bmat, hmat, 512);

    // --- fc2 -> p; theta -> d_out; grids
    fc2_kernel<<<200, 256, 0, stream>>>(hmat, fc2_w, pbuf);
    theta_grids_kernel<<<8, 256, 0, stream>>>(pbuf, gridb, outT);

    // --- grid_sample f_p -> im2col layout for conv_stn (reuse Bmat)
    gridsample_kernel<<<nIm, b256, 0, stream>>>(fbuf, gridb, Bmat);

    // --- conv_stn (bias folded into softmax read)
    hipMemsetAsync(stn, 0, 40200 * sizeof(float), stream);
    gemm200<<<dim3(4, 4, KSPLIT), b256, 0, stream>>>(conv_stn_w, Bmat, stn, 201);

    // --- joint softmax + outputs
    softmax_kernel<<<8, 256, 0, stream>>>(stn, conv_stn_b, outC, outS);
}

// Round 2
// 779.285 us; speedup vs baseline: 3.1112x; 3.1112x over previous
//
#include <hip/hip_runtime.h>
#include <hip/hip_bf16.h>

// ---------------------------------------------------------------------------
// Net_15762529976343 — R2: all five GEMMs (K=18432, N=200) on bf16 MFMA.
//   conv_last / loc1 / loc2 : M=2048   fc1 : M=512   conv_stn : M=201
// B matrices produced as bf16 [n][k] (transposed im2col) -> global_load_lds.
// A (fp32 weights) converted to bf16 in-GEMM via v_perm truncation.
// ---------------------------------------------------------------------------

#define GK 18432
#define GN 200
#define NPAD 256

typedef __attribute__((ext_vector_type(8))) short bf16x8;
typedef __attribute__((ext_vector_type(4))) float f32x4;
typedef unsigned int u32;

// ---------------- im2col: in [8,2048,H,H] fp32 -> Bt [NPAD][GK] bf16 -------
__global__ __launch_bounds__(256) void im2col_bf16(
    const float* __restrict__ in, __hip_bfloat16* __restrict__ Bt,
    int H, int stride, int pad)
{
    int tid = blockIdx.x * 256 + threadIdx.x;   // NPAD*GK exactly
    int n = tid / GK;
    int k = tid - n * GK;
    float v = 0.f;
    if (n < GN) {
        int c = k / 9; int r9 = k - c * 9;
        int kh = r9 / 3, kw = r9 - kh * 3;
        int b = n / 25; int pp = n - b * 25;
        int oh = pp / 5, ow = pp - oh * 5;
        int r = oh * stride + kh - pad;
        int s = ow * stride + kw - pad;
        if (r >= 0 && r < H && s >= 0 && s < H)
            v = in[(((b * 2048 + c) * H) + r) * H + s];
    }
    Bt[tid] = __float2bfloat16(v);
}

// ---------------- grid_sample of padded f -> Bt [NPAD][GK] bf16 ------------
__global__ __launch_bounds__(256) void gridsample_bf16(
    const float* __restrict__ f, const float* __restrict__ gridb,
    __hip_bfloat16* __restrict__ Bt)
{
    int tid = blockIdx.x * 256 + threadIdx.x;
    int n = tid / GK;
    int cq = tid - n * GK;
    float v = 0.f;
    if (n < GN) {
        int c = cq / 9, q = cq - c * 9;
        int b = n / 25, p = n - b * 25;
        int g = (b * 225 + p * 9 + q) * 2;
        float px = gridb[g], py = gridb[g + 1];
        float x0f = floorf(px), y0f = floorf(py);
        int x0 = (int)x0f, y0 = (int)y0f;
        float wx1 = px - x0f, wx0 = 1.f - wx1;
        float wy1 = py - y0f, wy0 = 1.f - wy1;
        const float* fb = f + ((size_t)b * 2048 + c) * 25;
        // padded 7x7: nonzero only for 1<=x<=5, 1<=y<=5
        auto fetch = [&](int xi, int yi) -> float {
            if (xi < 1 || xi > 5 || yi < 1 || yi > 5) return 0.f;
            return fb[(yi - 1) * 5 + (xi - 1)];
        };
        v = fetch(x0, y0) * wx0 * wy0
          + fetch(x0 + 1, y0) * wx1 * wy0
          + fetch(x0, y0 + 1) * wx0 * wy1
          + fetch(x0 + 1, y0 + 1) * wx1 * wy1;
    }
    Bt[tid] = __float2bfloat16(v);
}

// ---------------- MFMA GEMM: C[M,200] += A_f32[M,GK] * Bt_bf16[n][k]^T -----
// 128x128 tile, 4 waves of 64x64 (4x4 16x16x32 frags), BK=32, z=K-split.
__global__ __launch_bounds__(256) void gemm_mfma(
    const float* __restrict__ A, const __hip_bfloat16* __restrict__ Bt,
    float* __restrict__ C, int M, int kchunk)
{
    __shared__ unsigned short As[128 * 40];   // stride 40: bank-balanced
    __shared__ unsigned short Bs[128 * 32];   // stride 32: global_load_lds order

    const int tid = threadIdx.x;
    const int bn = blockIdx.x * 128;
    const int bm = blockIdx.y * 128;
    const int kbase = blockIdx.z * kchunk;

    const int wave = tid >> 6, lane = tid & 63;
    const int wm = (wave & 1) * 64, wn = (wave >> 1) * 64;
    const int lm = lane & 15, lq = lane >> 4;

    // A staging: thread -> (row, 16-elem half-row)
    const int arow = tid >> 1;
    const int akh = (tid & 1) * 16;
    const bool aok = (bm + arow) < M;
    const float* aptr = A + (size_t)(bm + arow) * GK + kbase + akh;
    uint4* awr = (uint4*)&As[arow * 40 + akh];

    // B staging: 2 global_load_lds calls/thread, wave-contiguous LDS
    const int brow = wave * 32 + (lane >> 2);
    const int bkoff = (lane & 3) * 8;
    const __hip_bfloat16* bptr0 = Bt + (size_t)(bn + brow) * GK + kbase + bkoff;
    const __hip_bfloat16* bptr1 = bptr0 + (size_t)16 * GK;
    unsigned short* bwr0 = &Bs[wave * 1024];
    unsigned short* bwr1 = &Bs[wave * 1024 + 512];

    f32x4 acc[4][4] = {};

    for (int k0 = 0; k0 < kchunk; k0 += 32) {
        __builtin_amdgcn_global_load_lds((const u32*)(bptr0 + k0), (u32*)bwr0, 16, 0, 0);
        __builtin_amdgcn_global_load_lds((const u32*)(bptr1 + k0), (u32*)bwr1, 16, 0, 0);

        u32 pk[8];
        if (aok) {
            const float4* ap = (const float4*)(aptr + k0);
            float4 a0 = ap[0], a1 = ap[1], a2 = ap[2], a3 = ap[3];
            pk[0] = __builtin_amdgcn_perm(__float_as_uint(a0.y), __float_as_uint(a0.x), 0x07060302u);
            pk[1] = __builtin_amdgcn_perm(__float_as_uint(a0.w), __float_as_uint(a0.z), 0x07060302u);
            pk[2] = __builtin_amdgcn_perm(__float_as_uint(a1.y), __float_as_uint(a1.x), 0x07060302u);
            pk[3] = __builtin_amdgcn_perm(__float_as_uint(a1.w), __float_as_uint(a1.z), 0x07060302u);
            pk[4] = __builtin_amdgcn_perm(__float_as_uint(a2.y), __float_as_uint(a2.x), 0x07060302u);
            pk[5] = __builtin_amdgcn_perm(__float_as_uint(a2.w), __float_as_uint(a2.z), 0x07060302u);
            pk[6] = __builtin_amdgcn_perm(__float_as_uint(a3.y), __float_as_uint(a3.x), 0x07060302u);
            pk[7] = __builtin_amdgcn_perm(__float_as_uint(a3.w), __float_as_uint(a3.z), 0x07060302u);
        } else {
#pragma unroll
            for (int i = 0; i < 8; ++i) pk[i] = 0;
        }
        awr[0] = make_uint4(pk[0], pk[1], pk[2], pk[3]);
        awr[1] = make_uint4(pk[4], pk[5], pk[6], pk[7]);

        __syncthreads();   // drains lds-direct loads + ds_writes

        bf16x8 af[4], bfr[4];
#pragma unroll
        for (int i = 0; i < 4; ++i) {
            af[i]  = *(const bf16x8*)&As[(wm + i * 16 + lm) * 40 + lq * 8];
            bfr[i] = *(const bf16x8*)&Bs[(wn + i * 16 + lm) * 32 + lq * 8];
        }
#pragma unroll
        for (int i = 0; i < 4; ++i)
#pragma unroll
            for (int j = 0; j < 4; ++j)
                acc[i][j] = __builtin_amdgcn_mfma_f32_16x16x32_bf16(
                    af[i], bfr[j], acc[i][j], 0, 0, 0);

        __syncthreads();   // protect LDS before next stage
    }

#pragma unroll
    for (int i = 0; i < 4; ++i) {
        int row0 = bm + wm + i * 16 + lq * 4;
#pragma unroll
        for (int j = 0; j < 4; ++j) {
            int col = bn + wn + j * 16 + lm;
            if (col < GN) {
#pragma unroll
                for (int r = 0; r < 4; ++r)
                    if (row0 + r < M)
                        atomicAdd(&C[(size_t)(row0 + r) * GN + col], acc[i][j][r]);
            }
        }
    }
}

// -------- BN stats: per-channel mean/rstd over 200 values ------------------
__global__ void bnstats_kernel(const float* __restrict__ y,
                               float* __restrict__ meanb,
                               float* __restrict__ rstdb)
{
    int ch = blockIdx.x;
    int lane = threadIdx.x;   // 64
    const float* p = y + (size_t)ch * GN;
    float s = 0.f, sq = 0.f;
    for (int idx = lane; idx < GN; idx += 64) {
        float v = p[idx];
        s += v; sq += v * v;
    }
    for (int off = 32; off; off >>= 1) {
        s += __shfl_down(s, off);
        sq += __shfl_down(sq, off);
    }
    if (lane == 0) {
        float m = s * (1.f / 200.f);
        float var = sq * (1.f / 200.f) - m * m;
        meanb[ch] = m;
        rstdb[ch] = rsqrtf(var + 1e-5f);
    }
}

// -------- BN apply + optional relu; [co][n] -> NCHW ------------------------
__global__ __launch_bounds__(256) void bn_apply_kernel(
    const float* __restrict__ y, const float* __restrict__ meanb,
    const float* __restrict__ rstdb, const float* __restrict__ g,
    const float* __restrict__ bb, float* __restrict__ out, int relu)
{
    int tid = blockIdx.x * 256 + threadIdx.x;   // 409600
    if (tid >= 409600) return;
    int b = tid / (2048 * 25);
    int rem = tid % (2048 * 25);
    int c = rem / 25;
    int pp = rem % 25;
    float v = y[(size_t)c * GN + b * 25 + pp];
    v = (v - meanb[c]) * rstdb[c] * g[c] + bb[c];
    if (relu) v = fmaxf(v, 0.f);
    out[tid] = v;
}

// -------- fc2 (relu of hmat folded here) -----------------------------------
__global__ void fc2_kernel(const float* __restrict__ hmat,
                           const float* __restrict__ fc2w,
                           float* __restrict__ pbuf)
{
    int n = blockIdx.x;            // 0..199
    int oo = threadIdx.x >> 6;     // 0..3
    int lane = threadIdx.x & 63;
    float s = 0.f;
#pragma unroll
    for (int j = 0; j < 8; ++j) {
        int hh = lane + 64 * j;
        s += fmaxf(hmat[(size_t)hh * GN + n], 0.f) * fc2w[oo * 512 + hh];
    }
    for (int off = 32; off; off >>= 1) s += __shfl_down(s, off);
    if (lane == 0) pbuf[n * 4 + oo] = s;
}

// -------- theta (d_out) + sampling grid pixel coords -----------------------
__global__ void theta_grids_kernel(const float* __restrict__ pbuf,
                                   float* __restrict__ gridb,
                                   float* __restrict__ outT)
{
    int tid = blockIdx.x * 256 + threadIdx.x;   // 1800
    if (tid >= 1800) return;
    int b = tid / 225;
    int rem = tid % 225;
    int p = rem / 9;
    int k = rem % 9;
    int i = p / 5, j = p % 5;
    int dy = k / 3, dx = k % 3;
    int n = b * 25 + p;
    float p0 = pbuf[n * 4 + 0];
    float p1 = pbuf[n * 4 + 1];
    float p2 = pbuf[n * 4 + 2];
    float p3 = pbuf[n * 4 + 3];
    float x = (float)(j + dx) * (1.f / 3.f) - 1.f;
    float y = (float)(i + dy) * (1.f / 3.f) - 1.f;
    float gx = (1.f + p0) * x + p1;
    float gy = (1.f + p2) * y + p3;
    gridb[tid * 2 + 0] = (gx + 1.f) * 3.f;
    gridb[tid * 2 + 1] = (gy + 1.f) * 3.f;
    if (k == 0) {
        outT[n * 6 + 0] = 1.f + p0;
        outT[n * 6 + 1] = 0.f;
        outT[n * 6 + 2] = p1;
        outT[n * 6 + 3] = 0.f;
        outT[n * 6 + 4] = 1.f + p2;
        outT[n * 6 + 5] = p3;
    }
}

// -------- softmax over 201*25 per batch (+bias) ----------------------------
__global__ void softmax_kernel(const float* __restrict__ stn,
                               const float* __restrict__ bias,
                               float* __restrict__ outC,
                               float* __restrict__ outS)
{
    int b = blockIdx.x;
    __shared__ float red[256];
    int t = threadIdx.x;

    float mx = -1e30f;
    for (int idx = t; idx < 5025; idx += 256) {
        int o = idx / 25, pp = idx % 25;
        mx = fmaxf(mx, stn[(size_t)o * GN + b * 25 + pp] + bias[o]);
    }
    red[t] = mx; __syncthreads();
    for (int s = 128; s; s >>= 1) {
        if (t < s) red[t] = fmaxf(red[t], red[t + s]);
        __syncthreads();
    }
    mx = red[0]; __syncthreads();

    float sm = 0.f;
    for (int idx = t; idx < 5025; idx += 256) {
        int o = idx / 25, pp = idx % 25;
        sm += expf(stn[(size_t)o * GN + b * 25 + pp] + bias[o] - mx);
    }
    red[t] = sm; __syncthreads();
    for (int s = 128; s; s >>= 1) {
        if (t < s) red[t] += red[t + s];
        __syncthreads();
    }
    float inv = 1.f / red[0];

    for (int idx = t; idx < 5025; idx += 256) {
        int o = idx / 25, pp = idx % 25;
        outS[b * 5025 + idx] =
            expf(stn[(size_t)o * GN + b * 25 + pp] + bias[o] - mx) * inv;
    }
    for (int o = t; o < 201; o += 256) {
        float cs = 0.f;
        for (int pp = 0; pp < 25; ++pp)
            cs += expf(stn[(size_t)o * GN + b * 25 + pp] + bias[o] - mx);
        outC[b * 201 + o] = cs * inv;
    }
}

// ---------------------------------------------------------------------------
extern "C" void kernel_launch(void* const* d_in, const int* in_sizes, int n_in,
                              void* d_out, int out_size, void* d_ws, size_t ws_size,
                              hipStream_t stream)
{
    const float* x           = (const float*)d_in[0];
    const float* conv_last_w = (const float*)d_in[3];
    const float* bn_last_g   = (const float*)d_in[4];
    const float* bn_last_b   = (const float*)d_in[5];
    const float* loc_w1      = (const float*)d_in[6];
    const float* loc_g1      = (const float*)d_in[7];
    const float* loc_b1      = (const float*)d_in[8];
    const float* loc_w2      = (const float*)d_in[9];
    const float* loc_g2      = (const float*)d_in[10];
    const float* loc_b2      = (const float*)d_in[11];
    const float* fc1_w       = (const float*)d_in[12];
    const float* fc2_w       = (const float*)d_in[13];
    const float* conv_stn_w  = (const float*)d_in[14];
    const float* conv_stn_b  = (const float*)d_in[15];

    __hip_bfloat16* Bt = (__hip_bfloat16*)d_ws;          // NPAD*GK bf16 = 9.44 MB
    float* fp    = (float*)((char*)d_ws + (size_t)NPAD * GK * 2);
    float* t1    = fp;                       // 409,600
    float* fbuf  = t1 + 409600;              // 409,600
    float* xs1   = fbuf + 409600;            // 409,600
    float* xs    = xs1 + 409600;             // 409,600
    float* hmat  = xs + 409600;              // 102,400
    float* stn   = hmat + 102400;            // 40,200
    float* pbuf  = stn + 40200;              // 800
    float* gridb = pbuf + 800;               // 3,600
    float* meanb = gridb + 3600;             // 2,048
    float* rstdb = meanb + 2048;             // 2,048

    float* outC = (float*)d_out;             // [8,201]
    float* outS = outC + 8 * 201;            // [8,201,5,5]
    float* outT = outS + 8 * 201 * 25;       // [200,2,3]

    dim3 b256(256);
    const int nB = (NPAD * GK) / 256;        // 18432 blocks

    // conv_last (s2,p1) + bn -> fbuf
    im2col_bf16<<<nB, b256, 0, stream>>>(x, Bt, 10, 2, 1);
    hipMemsetAsync(t1, 0, 409600 * sizeof(float), stream);
    gemm_mfma<<<dim3(2, 16, 16), b256, 0, stream>>>(conv_last_w, Bt, t1, 2048, GK / 16);
    bnstats_kernel<<<2048, 64, 0, stream>>>(t1, meanb, rstdb);
    bn_apply_kernel<<<1600, b256, 0, stream>>>(t1, meanb, rstdb, bn_last_g, bn_last_b, fbuf, 0);

    // loc conv1 + bn + relu -> xs1
    im2col_bf16<<<nB, b256, 0, stream>>>(fbuf, Bt, 5, 1, 1);
    hipMemsetAsync(t1, 0, 409600 * sizeof(float), stream);
    gemm_mfma<<<dim3(2, 16, 16), b256, 0, stream>>>(loc_w1, Bt, t1, 2048, GK / 16);
    bnstats_kernel<<<2048, 64, 0, stream>>>(t1, meanb, rstdb);
    bn_apply_kernel<<<1600, b256, 0, stream>>>(t1, meanb, rstdb, loc_g1, loc_b1, xs1, 1);

    // loc conv2 + bn + relu -> xs
    im2col_bf16<<<nB, b256, 0, stream>>>(xs1, Bt, 5, 1, 1);
    hipMemsetAsync(t1, 0, 409600 * sizeof(float), stream);
    gemm_mfma<<<dim3(2, 16, 16), b256, 0, stream>>>(loc_w2, Bt, t1, 2048, GK / 16);
    bnstats_kernel<<<2048, 64, 0, stream>>>(t1, meanb, rstdb);
    bn_apply_kernel<<<1600, b256, 0, stream>>>(t1, meanb, rstdb, loc_g2, loc_b2, xs, 1);

    // fc1 (patches == im2col(xs)); relu folded into fc2 read
    im2col_bf16<<<nB, b256, 0, stream>>>(xs, Bt, 5, 1, 1);
    hipMemsetAsync(hmat, 0, 102400 * sizeof(float), stream);
    gemm_mfma<<<dim3(2, 4, 32), b256, 0, stream>>>(fc1_w, Bt, hmat, 512, GK / 32);

    // fc2 -> p; theta -> d_out; grids
    fc2_kernel<<<200, 256, 0, stream>>>(hmat, fc2_w, pbuf);
    theta_grids_kernel<<<8, 256, 0, stream>>>(pbuf, gridb, outT);

    // grid_sample -> Bt (im2col layout of temp)
    gridsample_bf16<<<nB, b256, 0, stream>>>(fbuf, gridb, Bt);

    // conv_stn (bias folded into softmax)
    hipMemsetAsync(stn, 0, 40200 * sizeof(float), stream);
    gemm_mfma<<<dim3(2, 2, 32), b256, 0, stream>>>(conv_stn_w, Bt, stn, 201, GK / 32);

    // softmax + outputs
    softmax_kernel<<<8, 256, 0, stream>>>(stn, conv_stn_b, outC, outS);
}